// Round 14
// baseline (336.782 us; speedup 1.0000x reference)
//
#include <hip/hip_runtime.h>
#include <hip/hip_bf16.h>

#define B_ROWS 65536
#define D_IN   128
#define H_DIM  512
#define E_DIM  64
#define K_CODES 4096

typedef __bf16 bf16;
typedef __attribute__((ext_vector_type(8))) __bf16 bf16x8;
typedef __attribute__((ext_vector_type(4))) float f32x4;

// async global->LDS, 16 B per lane; LDS dest = wave-uniform base + lane*16
__device__ __forceinline__ void gld_lds16(const bf16* g, bf16* l)
{
    __builtin_amdgcn_global_load_lds((const __attribute__((address_space(1))) void*)g,
                                     (__attribute__((address_space(3))) void*)l,
                                     16, 0, 0);
}

// ---------------------------------------------------------------------------
// mfma_gemm2: proven BM=128/BK=32 single-barrier double-buffered loop,
// BN=128, TWO runtime problem descriptors per dispatch (R11: 359->333.7us).
// ---------------------------------------------------------------------------
struct GemmProb {
    const void* Ap; const bf16* WT;
    const float* scale; const float* shift;
    void* Cout;
    int N, K, NCB, nblk;   // nblk = (M/128)*NCB
};

template<bool CONV_A, bool RELU>
__global__ __launch_bounds__(256, 4)
void mfma_gemm2(GemmProb pA, GemmProb pB)
{
    __shared__ bf16 As[2][128 * 32];
    __shared__ bf16 Bs[2][128 * 32];

    const int tid  = threadIdx.x;
    const int lane = tid & 63;
    const int wv   = tid >> 6;
    const int wm   = wv >> 1, wn = wv & 1;
    const int l16  = lane & 15, quad = lane >> 4;

    const bool second = (int)blockIdx.x >= pA.nblk;
    const GemmProb p = second ? pB : pA;
    const int bid = second ? (int)blockIdx.x - pA.nblk : (int)blockIdx.x;
    const int N = p.N, K = p.K, NCB = p.NCB;

    const int P = p.nblk / NCB;
    int panel, colb;
    if (NCB == 1 || (P & 7) != 0) {
        panel = bid % P;
        colb  = bid / P;
    } else {
        int xcd = bid & 7;
        int loc = bid >> 3;
        panel = xcd * (P >> 3) + loc / NCB;
        colb  = loc % NCB;
    }
    const size_t m0 = (size_t)panel * 128;
    const int  n0  = colb * 128;
    const int  csw = quad ^ ((l16 >> 1) & 3);
    const int  nk  = K >> 5;

    auto stage = [&](int s, int k0) {
        if constexpr (CONV_A) {
            const float* Af = (const float*)p.Ap;
#pragma unroll
            for (int ii = 0; ii < 2; ++ii) {
                int u = (wv + ii * 4) * 64 + lane;
                int r = u >> 2;
                int kg = (u & 3) ^ ((r >> 1) & 3);
                const float* src = Af + (m0 + r) * K + k0 + kg * 8;
                float4 v0 = *(const float4*)src;
                float4 v1 = *(const float4*)(src + 4);
                bf16 t[8] = {(bf16)v0.x, (bf16)v0.y, (bf16)v0.z, (bf16)v0.w,
                             (bf16)v1.x, (bf16)v1.y, (bf16)v1.z, (bf16)v1.w};
                *(bf16x8*)&As[s][u * 8] = *(bf16x8*)t;
            }
        } else {
            const bf16* Ab = (const bf16*)p.Ap;
#pragma unroll
            for (int ii = 0; ii < 2; ++ii) {
                int i = wv + ii * 4;
                int u = i * 64 + lane;
                int r = u >> 2;
                int kg = (u & 3) ^ ((r >> 1) & 3);
                gld_lds16(Ab + (m0 + r) * K + k0 + kg * 8, &As[s][i * 512]);
            }
        }
#pragma unroll
        for (int ii = 0; ii < 2; ++ii) {
            int i = wv + ii * 4;
            int u = i * 64 + lane;
            int r = u >> 2;
            int kg = (u & 3) ^ ((r >> 1) & 3);
            gld_lds16(p.WT + (size_t)(n0 + r) * K + k0 + kg * 8, &Bs[s][i * 512]);
        }
    };

    f32x4 acc[4][4] = {};
    stage(0, 0);
    for (int kt = 0; kt < nk; ++kt) {
        __syncthreads();
        if (kt + 1 < nk) stage((kt + 1) & 1, (kt + 1) * 32);
        const bf16* as = As[kt & 1];
        const bf16* bs = Bs[kt & 1];
        bf16x8 af[4], bfr[4];
#pragma unroll
        for (int i = 0; i < 4; ++i)
            af[i] = *(const bf16x8*)&as[(wm * 64 + i * 16 + l16) * 32 + csw * 8];
#pragma unroll
        for (int j = 0; j < 4; ++j)
            bfr[j] = *(const bf16x8*)&bs[(wn * 64 + j * 16 + l16) * 32 + csw * 8];
#pragma unroll
        for (int i = 0; i < 4; ++i)
#pragma unroll
            for (int j = 0; j < 4; ++j)
                acc[i][j] = __builtin_amdgcn_mfma_f32_16x16x32_bf16(af[i], bfr[j], acc[i][j], 0, 0, 0);
    }

#pragma unroll
    for (int i = 0; i < 4; ++i) {
#pragma unroll
        for (int j = 0; j < 4; ++j) {
            int col = n0 + wn * 64 + j * 16 + l16;
            float sc = p.scale ? p.scale[col] : 1.0f;
            float sh = p.shift[col];
#pragma unroll
            for (int r = 0; r < 4; ++r) {
                size_t row = m0 + wm * 64 + i * 16 + quad * 4 + r;
                float v = acc[i][j][r];
                v *= sc;
                v += sh;
                if (RELU) v = fmaxf(v, 0.0f);
                ((bf16*)p.Cout)[row * (size_t)N + col] = (bf16)v;
            }
        }
    }
}

// ---------------------------------------------------------------------------
// mfma_gemm4: dual-path G4 dispatch. Encoder path reworked to BM=64xBN=64
// (R14): Penc = M/64 = 1024 blocks = exactly 4 blocks/CU — one full cohort
// with 4 independent barrier groups (session-verified lever; was 512 blocks
// = 2/CU = the measured-bad 2-group regime). 4 waves in 2x2 over rows/cols,
// acc 2x2 fragments, 1 gld_lds16/thread/matrix/iter, K=256 -> 8 iters.
// Epilogue addition tree identical (2 waves x 2 j x 16 lanes per row) ->
// bit-identical results. Blocks [Penc,Penc+32): mini-G4 (BM=128, K=512,
// OUT_F32 -> XRcb), unchanged.
// ---------------------------------------------------------------------------
__global__ __launch_bounds__(256, 4)
void mfma_gemm4(const bf16* __restrict__ Xb, const bf16* __restrict__ W4T,
                const float* __restrict__ b4, bf16* __restrict__ zb,
                bf16* __restrict__ zn, int Penc,
                const bf16* __restrict__ XR3, const bf16* __restrict__ D4T,
                const float* __restrict__ db4, float* __restrict__ XRcb)
{
    __shared__ bf16 As[2][128 * 32];
    __shared__ bf16 Bs[2][128 * 32];
    __shared__ float nrm2[128];

    const int tid  = threadIdx.x;
    const int lane = tid & 63;
    const int wv   = tid >> 6;
    const int wm   = wv >> 1, wn = wv & 1;
    const int l16  = lane & 15, quad = lane >> 4;
    const int csw  = quad ^ ((l16 >> 1) & 3);

    if ((int)blockIdx.x < Penc) {
        // ---- encoder G4: BM=64, BN=64, K=256, FUSE_ZN ----
        const size_t m0 = (size_t)blockIdx.x * 64;
        const int K = 256;

        auto stage = [&](int s, int k0) {
            int u = wv * 64 + lane;              // 0..255
            int r = u >> 2;                      // row 0..63
            int kg = (u & 3) ^ ((r >> 1) & 3);
            gld_lds16(Xb + (m0 + r) * K + k0 + kg * 8, &As[s][wv * 512]);
            gld_lds16(W4T + (size_t)r * K + k0 + kg * 8, &Bs[s][wv * 512]);
        };

        f32x4 acc[2][2] = {};
        stage(0, 0);
        for (int kt = 0; kt < 8; ++kt) {
            __syncthreads();
            if (kt + 1 < 8) stage((kt + 1) & 1, (kt + 1) * 32);
            const bf16* as = As[kt & 1];
            const bf16* bs = Bs[kt & 1];
            bf16x8 af[2], bfr[2];
#pragma unroll
            for (int i = 0; i < 2; ++i)
                af[i] = *(const bf16x8*)&as[(wm * 32 + i * 16 + l16) * 32 + csw * 8];
#pragma unroll
            for (int j = 0; j < 2; ++j)
                bfr[j] = *(const bf16x8*)&bs[(wn * 32 + j * 16 + l16) * 32 + csw * 8];
#pragma unroll
            for (int i = 0; i < 2; ++i)
#pragma unroll
                for (int j = 0; j < 2; ++j)
                    acc[i][j] = __builtin_amdgcn_mfma_f32_16x16x32_bf16(af[i], bfr[j], acc[i][j], 0, 0, 0);
        }

        float vv[2][2][4];
        float pp[2][4];
#pragma unroll
        for (int i = 0; i < 2; ++i)
#pragma unroll
            for (int r = 0; r < 4; ++r) {
                float s = 0.f;
#pragma unroll
                for (int j = 0; j < 2; ++j) {
                    int col = wn * 32 + j * 16 + l16;
                    float v = acc[i][j][r] + b4[col];
                    vv[i][j][r] = v;
                    s = fmaf(v, v, s);
                }
                pp[i][r] = s;
            }
#pragma unroll
        for (int off = 1; off < 16; off <<= 1)
#pragma unroll
            for (int i = 0; i < 2; ++i)
#pragma unroll
                for (int r = 0; r < 4; ++r)
                    pp[i][r] += __shfl_xor(pp[i][r], off, 64);
        if (l16 == 0) {
#pragma unroll
            for (int i = 0; i < 2; ++i)
#pragma unroll
                for (int r = 0; r < 4; ++r)
                    nrm2[wn * 64 + wm * 32 + i * 16 + quad * 4 + r] = pp[i][r];
        }
        __syncthreads();
#pragma unroll
        for (int i = 0; i < 2; ++i)
#pragma unroll
            for (int r = 0; r < 4; ++r) {
                int rl = wm * 32 + i * 16 + quad * 4 + r;
                float s2 = nrm2[rl] + nrm2[64 + rl];
                float rn = 0.5f / fmaxf(sqrtf(s2), 1e-12f);
                size_t row = m0 + rl;
#pragma unroll
                for (int j = 0; j < 2; ++j) {
                    int col = wn * 32 + j * 16 + l16;
                    float v = vv[i][j][r];
                    zb[row * 64 + col] = (bf16)v;
                    zn[row * 64 + col] = (bf16)(v * rn);
                }
            }
    } else {
        // ---- mini G4: 4096x128x512, OUT_F32 -> XRcb ----
        const size_t m0 = (size_t)((int)blockIdx.x - Penc) * 128;
        const int K = 512;

        auto stage = [&](int s, int k0) {
#pragma unroll
            for (int ii = 0; ii < 2; ++ii) {
                int i = wv + ii * 4;
                int u = i * 64 + lane;
                int r = u >> 2;
                int kg = (u & 3) ^ ((r >> 1) & 3);
                gld_lds16(XR3 + (m0 + r) * K + k0 + kg * 8, &As[s][i * 512]);
            }
#pragma unroll
            for (int ii = 0; ii < 2; ++ii) {
                int i = wv + ii * 4;
                int u = i * 64 + lane;
                int r = u >> 2;
                int kg = (u & 3) ^ ((r >> 1) & 3);
                gld_lds16(D4T + (size_t)r * K + k0 + kg * 8, &Bs[s][i * 512]);
            }
        };

        f32x4 acc[4][4] = {};
        stage(0, 0);
        for (int kt = 0; kt < 16; ++kt) {
            __syncthreads();
            if (kt + 1 < 16) stage((kt + 1) & 1, (kt + 1) * 32);
            const bf16* as = As[kt & 1];
            const bf16* bs = Bs[kt & 1];
            bf16x8 af[4], bfr[4];
#pragma unroll
            for (int i = 0; i < 4; ++i)
                af[i] = *(const bf16x8*)&as[(wm * 64 + i * 16 + l16) * 32 + csw * 8];
#pragma unroll
            for (int j = 0; j < 4; ++j)
                bfr[j] = *(const bf16x8*)&bs[(wn * 64 + j * 16 + l16) * 32 + csw * 8];
#pragma unroll
            for (int i = 0; i < 4; ++i)
#pragma unroll
                for (int j = 0; j < 4; ++j)
                    acc[i][j] = __builtin_amdgcn_mfma_f32_16x16x32_bf16(af[i], bfr[j], acc[i][j], 0, 0, 0);
        }

#pragma unroll
        for (int i = 0; i < 4; ++i) {
#pragma unroll
            for (int j = 0; j < 4; ++j) {
                int col = wn * 64 + j * 16 + l16;
                float sh = db4[col];
#pragma unroll
                for (int r = 0; r < 4; ++r) {
                    size_t row = m0 + wm * 64 + i * 16 + quad * 4 + r;
                    XRcb[row * 128 + col] = acc[i][j][r] + sh;
                }
            }
        }
    }
}

// ---------------------------------------------------------------------------
// prep_transp: merged prep_misc + transp_all (both independent, input-only).
// blocks 0..1023 -> en; 1024..1039 -> zero counts; 1040 -> BN fold;
// 1041.. -> the 8 weight transposes.
// ---------------------------------------------------------------------------
struct TranspArgs { const float* s[8]; bf16* d[8]; };

__global__ __launch_bounds__(256)
void prep_transp(const float* __restrict__ emb, bf16* __restrict__ en,
                 unsigned int* __restrict__ counts,
                 const float* __restrict__ b1, const float* __restrict__ g1,
                 const float* __restrict__ be1, const float* __restrict__ rm1,
                 const float* __restrict__ rv1,
                 float* __restrict__ s1, float* __restrict__ sh1,
                 TranspArgs a)
{
    __shared__ float T[64][65];
    const int bid = blockIdx.x;
    const int tid = threadIdx.x;
    if (bid < 1024) {
        int lane = tid & 63;
        int row = bid * 4 + (tid >> 6);
        float v = emb[(size_t)row * E_DIM + lane];
        float ss = v * v;
#pragma unroll
        for (int o = 32; o > 0; o >>= 1) ss += __shfl_xor(ss, o, 64);
        float n = fmaxf(sqrtf(ss), 1e-12f);
        en[(size_t)row * E_DIM + lane] = (bf16)(v / n);
        return;
    }
    if (bid < 1040) {
        counts[(bid - 1024) * 256 + tid] = 0u;
        return;
    }
    if (bid == 1040) {
        for (int j = tid; j < H_DIM; j += 256) {
            float s = g1[j] * (1.0f / sqrtf(rv1[j] + 1e-5f));
            s1[j] = s;
            sh1[j] = (b1[j] - rm1[j]) * s + be1[j];
        }
        return;
    }
    // ---- transposes (bid-1041 in 0..231) ----
    constexpr int KS[8]  = {128, 512, 512, 256,  64, 256, 512, 512};
    constexpr int NS[8]  = {512, 512, 256,  64, 256, 512, 512, 128};
    constexpr int CUM[9] = {0, 16, 80, 112, 116, 120, 152, 216, 232};
    int tb = bid - 1041;
    int seg = 0;
#pragma unroll
    for (int s = 0; s < 8; ++s)
        if (tb >= CUM[s + 1]) seg = s + 1;
    const int bt = tb - CUM[seg];
    const int K = KS[seg], N = NS[seg];
    const int tiles_n = N / 64;
    const int k0 = (bt / tiles_n) * 64;
    const int n0 = (bt % tiles_n) * 64;
    const float* src = a.s[seg];
    bf16* dst = a.d[seg];

    const int rr = tid >> 6, cc = tid & 63;
#pragma unroll
    for (int pp = 0; pp < 16; ++pp) {
        int row = pp * 4 + rr;
        T[row][cc] = src[(size_t)(k0 + row) * N + n0 + cc];
    }
    __syncthreads();
#pragma unroll
    for (int pp = 0; pp < 16; ++pp) {
        int row = pp * 4 + rr;
        dst[(size_t)(n0 + row) * K + k0 + cc] = (bf16)T[cc][row];
    }
}

// ---------------------------------------------------------------------------
// vq_all: R6-verified structure (71.6us): 64 rows/block, 128-code LDS tiles,
// transposed wave->code mapping (wave owns 32-code slice, scans all 64 rows
// in registers; 4 ds_read_b128/wave/tile), packed-u8 LDS histogram,
// global count atomics at kernel end. 4 blocks/CU — the measured optimum
// (3grp=93, 4grp=71.6, 7grp/2x-barriers=99, 2grp=143).
// ---------------------------------------------------------------------------
__global__ __launch_bounds__(256, 4)
void vq_all(const bf16* __restrict__ zn, const bf16* __restrict__ zb,
            const bf16* __restrict__ en, const float* __restrict__ emb,
            const float* __restrict__ XR, float* __restrict__ xout,
            unsigned int* __restrict__ counts, float* __restrict__ psum, int gb0)
{
    __shared__ bf16 es[2][128 * 64];
    __shared__ unsigned hcnt[K_CODES / 4];   // 4 x u8 per word
    __shared__ int idxs[64];
    __shared__ float red[256];               // reused: u32 wave-best, then f32 reduce
    const int tid = threadIdx.x;
    const int lane = tid & 63;
    const int wv = tid >> 6;
    const int l16 = lane & 15, quad = lane >> 4;
    const long r0 = (long)blockIdx.x * 64;

    // A-fragments for ALL 64 rows of this block (rows are block-shared;
    // codes are wave-private). 8 x bf16x8 = 32 VGPRs.
    bf16x8 a0[4], a1[4];
#pragma unroll
    for (int rg = 0; rg < 4; ++rg) {
        long arow = r0 + rg * 16 + l16;
        a0[rg] = *(const bf16x8*)&zn[arow * E_DIM + quad * 8];
        a1[rg] = *(const bf16x8*)&zn[arow * E_DIM + 32 + quad * 8];
    }

    auto stage = [&](int s, int c0) {
#pragma unroll
        for (int ii = 0; ii < 4; ++ii) {
            int i = wv + ii * 4;
            int u = i * 64 + lane;
            int r = u >> 3;
            int kg = (u & 7) ^ (r & 7);
            gld_lds16(en + (size_t)(c0 + r) * E_DIM + kg * 8, &es[s][i * 512]);
        }
    };

    for (int j = tid; j < K_CODES / 4; j += 256) hcnt[j] = 0u;

    unsigned best[4][4];
#pragma unroll
    for (int rg = 0; rg < 4; ++rg)
#pragma unroll
        for (int r = 0; r < 4; ++r) best[rg][r] = 0u;
    const unsigned MASKHI = 0xFFFFF000u;

    stage(0, 0);
    for (int c0 = 0; c0 < K_CODES; c0 += 128) {
        __syncthreads();
        if (c0 + 128 < K_CODES) stage(((c0 >> 7) + 1) & 1, c0 + 128);
        const bf16* e = es[(c0 >> 7) & 1];
#pragma unroll
        for (int cg = 0; cg < 2; ++cg) {
            int srow = wv * 32 + cg * 16 + l16;      // code row within tile
            bf16x8 b0 = *(const bf16x8*)&e[srow * 64 + ((quad ^ (srow & 7)) * 8)];
            bf16x8 b1 = *(const bf16x8*)&e[srow * 64 + (((quad + 4) ^ (srow & 7)) * 8)];
            unsigned inv = (unsigned)(4095 - (c0 + srow));
#pragma unroll
            for (int rg = 0; rg < 4; ++rg) {
                f32x4 acc = {1.5f, 1.5f, 1.5f, 1.5f};
                acc = __builtin_amdgcn_mfma_f32_16x16x32_bf16(a0[rg], b0, acc, 0, 0, 0);
                acc = __builtin_amdgcn_mfma_f32_16x16x32_bf16(a1[rg], b1, acc, 0, 0, 0);
#pragma unroll
                for (int r = 0; r < 4; ++r) {
                    unsigned pk = (__float_as_uint(acc[r]) & MASKHI) | inv;
                    best[rg][r] = best[rg][r] > pk ? best[rg][r] : pk;
                }
            }
        }
    }
    // reduce across the 16 code-lanes (l16) for each of the 16 (rg,r) rows
#pragma unroll
    for (int off = 1; off < 16; off <<= 1) {
#pragma unroll
        for (int rg = 0; rg < 4; ++rg)
#pragma unroll
            for (int r = 0; r < 4; ++r) {
                unsigned o = (unsigned)__shfl_xor((int)best[rg][r], off, 64);
                best[rg][r] = best[rg][r] > o ? best[rg][r] : o;
            }
    }
    // per-wave per-row candidates -> LDS (red[] reused as u32 scratch)
    if (l16 == 0) {
        unsigned* wbest = (unsigned*)red;
#pragma unroll
        for (int rg = 0; rg < 4; ++rg)
#pragma unroll
            for (int r = 0; r < 4; ++r)
                wbest[wv * 64 + rg * 16 + quad * 4 + r] = best[rg][r];
    }
    __syncthreads();
    if (tid < 64) {
        const unsigned* wbest = (const unsigned*)red;
        unsigned m0 = wbest[tid],       m1 = wbest[64 + tid];
        unsigned m2 = wbest[128 + tid], m3 = wbest[192 + tid];
        unsigned m = m0 > m1 ? m0 : m1;
        unsigned n = m2 > m3 ? m2 : m3;
        m = m > n ? m : n;
        int b = 4095 - (int)(m & 0xFFFu);
        idxs[tid] = b;
        atomicAdd(&hcnt[b >> 2], 1u << ((b & 3) * 8));
    }
    __syncthreads();

    // post phase: wave wv handles rows wv, wv+4, ...
    float local = 0.f;
#pragma unroll 4
    for (int i = 0; i < 16; ++i) {
        int rl = wv + 4 * i;
        long row = r0 + rl;
        int id = idxs[rl] & (K_CODES - 1);
        float qv = emb[(size_t)id * E_DIM + lane];
        float zv = (float)zb[row * E_DIM + lane];
        float d = qv - zv;
        local = fmaf(d, d, local);
        float2 xv = *(const float2*)(XR + (size_t)id * D_IN + 2 * lane);
        float* dst = xout + (size_t)row * D_IN + 2 * lane;
        dst[0] = xv.x;
        dst[1] = xv.y;
    }
    red[tid] = local;
    __syncthreads();
    for (int s = 128; s > 0; s >>= 1) {
        if (tid < s) red[tid] += red[tid + s];
        __syncthreads();
    }
    if (tid == 0) psum[gb0 + blockIdx.x] = red[0];
    for (int j = tid; j < K_CODES / 4; j += 256) {
        unsigned w = hcnt[j];
        if (w) {
#pragma unroll
            for (int k = 0; k < 4; ++k) {
                unsigned c = (w >> (k * 8)) & 255u;
                if (c) atomicAdd(&counts[j * 4 + k], c);
            }
        }
    }
}

// ---------------------------------------------------------------------------
__global__ __launch_bounds__(1024)
void finalize_k(const unsigned int* __restrict__ counts, const float* __restrict__ psum,
                float* __restrict__ out_loss, float* __restrict__ out_perp)
{
    __shared__ float red[1024];
    const int tid = threadIdx.x;
    red[tid] = psum[tid];
    __syncthreads();
    for (int s = 512; s > 0; s >>= 1) {
        if (tid < s) red[tid] += red[tid + s];
        __syncthreads();
    }
    if (tid == 0)
        out_loss[0] = 1.02f * (red[0] * (1.0f / ((float)B_ROWS * (float)E_DIM)));
    __syncthreads();
    float e = 0.f;
    for (int j = tid; j < K_CODES; j += 1024) {
        float pr = (float)counts[j] * (1.0f / (float)B_ROWS);
        e += pr * logf(pr + 1e-10f);
    }
    red[tid] = e;
    __syncthreads();
    for (int s = 512; s > 0; s >>= 1) {
        if (tid < s) red[tid] += red[tid + s];
        __syncthreads();
    }
    if (tid == 0) out_perp[0] = expf(-red[0]);
}

// ---------------------------------------------------------------------------
extern "C" void kernel_launch(void* const* d_in, const int* in_sizes, int n_in,
                              void* d_out, int out_size, void* d_ws, size_t ws_size,
                              hipStream_t stream)
{
    const float* x   = (const float*)d_in[0];
    const float* W1  = (const float*)d_in[1];
    const float* b1  = (const float*)d_in[2];
    const float* g1  = (const float*)d_in[3];
    const float* be1 = (const float*)d_in[4];
    const float* rm1 = (const float*)d_in[5];
    const float* rv1 = (const float*)d_in[6];
    const float* W2  = (const float*)d_in[7];
    const float* b2  = (const float*)d_in[8];
    const float* W3  = (const float*)d_in[9];
    const float* b3  = (const float*)d_in[10];
    const float* W4  = (const float*)d_in[11];
    const float* b4  = (const float*)d_in[12];
    const float* emb = (const float*)d_in[13];
    const float* Dw1 = (const float*)d_in[14];
    const float* db1 = (const float*)d_in[15];
    const float* Dw2 = (const float*)d_in[16];
    const float* db2 = (const float*)d_in[17];
    const float* Dw3 = (const float*)d_in[18];
    const float* db3 = (const float*)d_in[19];
    const float* Dw4 = (const float*)d_in[20];
    const float* db4 = (const float*)d_in[21];
    float* out = (float*)d_out;
    (void)in_sizes; (void)n_in;

    // ---- workspace carve-up (256B-aligned) ----
    char* p = (char*)d_ws;
    size_t off = 0;
    auto alloc = [&](size_t bytes) -> char* {
        char* r = p + off;
        off = (off + bytes + 255) & ~(size_t)255;
        return r;
    };
    bf16* en  = (bf16*)alloc((size_t)K_CODES * E_DIM * 2);
    bf16* W1T = (bf16*)alloc((size_t)D_IN * H_DIM * 2);
    bf16* W2T = (bf16*)alloc((size_t)H_DIM * H_DIM * 2);
    bf16* W3T = (bf16*)alloc((size_t)H_DIM * (H_DIM / 2) * 2);
    bf16* W4T = (bf16*)alloc((size_t)(H_DIM / 2) * E_DIM * 2);
    bf16* D1T = (bf16*)alloc((size_t)E_DIM * (H_DIM / 2) * 2);
    bf16* D2T = (bf16*)alloc((size_t)(H_DIM / 2) * H_DIM * 2);
    bf16* D3T = (bf16*)alloc((size_t)H_DIM * H_DIM * 2);
    bf16* D4T = (bf16*)alloc((size_t)H_DIM * D_IN * 2);
    float* s1  = (float*)alloc(H_DIM * 4);
    float* sh1 = (float*)alloc(H_DIM * 4);
    unsigned int* counts = (unsigned int*)alloc(K_CODES * 4);
    float* psum = (float*)alloc((B_ROWS / 64) * 4);
    // mini decoder-on-codebook buffers
    bf16*  XR1  = (bf16*)alloc((size_t)K_CODES * (H_DIM / 2) * 2);  // 4096x256
    bf16*  XR2  = (bf16*)alloc((size_t)K_CODES * H_DIM * 2);        // 4096x512
    bf16*  XR3  = (bf16*)alloc((size_t)K_CODES * H_DIM * 2);        // 4096x512
    float* XRcb = (float*)alloc((size_t)K_CODES * D_IN * 4);        // 4096x128 f32
    size_t fixed_bytes = off;

    // per-chunk: Xb CH*1024 + Yb CH*1024 + zb CH*128 + zn CH*128
    int CH = 128;
    for (int c = B_ROWS; c >= 128; c >>= 1) {
        if (fixed_bytes + (size_t)c * 2304 + 4096 <= ws_size) { CH = c; break; }
    }
    bf16* Xb = (bf16*)alloc((size_t)CH * H_DIM * 2);
    bf16* Yb = (bf16*)alloc((size_t)CH * H_DIM * 2);
    bf16* zb = (bf16*)alloc((size_t)CH * E_DIM * 2);
    bf16* zn = (bf16*)alloc((size_t)CH * E_DIM * 2);

    // ---- prep + transposes, one dispatch ----
    TranspArgs ta;
    ta.s[0] = W1;  ta.d[0] = W1T;
    ta.s[1] = W2;  ta.d[1] = W2T;
    ta.s[2] = W3;  ta.d[2] = W3T;
    ta.s[3] = W4;  ta.d[3] = W4T;
    ta.s[4] = Dw1; ta.d[4] = D1T;
    ta.s[5] = Dw2; ta.d[5] = D2T;
    ta.s[6] = Dw3; ta.d[6] = D3T;
    ta.s[7] = Dw4; ta.d[7] = D4T;
    prep_transp<<<1041 + 232, 256, 0, stream>>>(emb, en, counts, b1, g1, be1, rm1, rv1, s1, sh1, ta);

    dim3 blk(256);
    const GemmProb NONE = {nullptr, nullptr, nullptr, nullptr, nullptr, 0, 0, 1, 0};

    for (int c0 = 0; c0 < B_ROWS; c0 += CH) {
        const int M = CH;
        const int P = M / 128;
        const bool z = (c0 == 0);   // zip the one-time mini decoder chain
                                    // (XRcb[c]=dec(emb[c])) into chunk 0's
                                    // encoder dispatches as extra blocks

        GemmProb e1 = {x + (size_t)c0 * D_IN, W1T, s1, sh1, Xb, 512, 128, 4, P * 4};
        GemmProb m1 = {emb, D1T, nullptr, db1, XR1, 256, 64, 2, 64};
        mfma_gemm2<true , true><<<e1.nblk + (z ? m1.nblk : 0), blk, 0, stream>>>(e1, z ? m1 : NONE);

        GemmProb e2 = {Xb, W2T, nullptr, b2, Yb, 512, 512, 4, P * 4};
        GemmProb m2 = {XR1, D2T, nullptr, db2, XR2, 512, 256, 4, 128};
        mfma_gemm2<false, true><<<e2.nblk + (z ? m2.nblk : 0), blk, 0, stream>>>(e2, z ? m2 : NONE);

        GemmProb e3 = {Yb, W3T, nullptr, b3, Xb, 256, 512, 2, P * 2};
        GemmProb m3 = {XR2, D3T, nullptr, db3, XR3, 512, 512, 4, 128};
        mfma_gemm2<false, true><<<e3.nblk + (z ? m3.nblk : 0), blk, 0, stream>>>(e3, z ? m3 : NONE);

        // G4: encoder FUSE_ZN at BM=64 (2P blocks = 4/CU) + zipped mini-G4
        mfma_gemm4<<<P * 2 + (z ? 32 : 0), blk, 0, stream>>>(Xb, W4T, b4, zb, zn, P * 2,
                                                             XR3, D4T, db4, XRcb);

        // VQ: argmin + histogram + sumsq + x_recon scatter, one kernel
        vq_all<<<M / 64, 256, 0, stream>>>(zn, zb, en, emb, XRcb,
                                           out + 1 + (size_t)c0 * D_IN,
                                           counts, psum, c0 / 64);
    }

    finalize_k<<<1, 1024, 0, stream>>>(counts, psum, out, out + (out_size - 1));
}